// Round 19
// baseline (199.318 us; speedup 1.0000x reference)
//
#include <hip/hip_runtime.h>

// Problem constants
#define B_   4
#define V_   8
#define L_   256
#define C_   1024
#define H_   16
#define O_   4
#define DH_  64
#define BV_  32      // B*V
#define M_   8192    // B*V*L
#define MB_  (1024 * 1024)

typedef short bf16x8 __attribute__((ext_vector_type(8)));
typedef short bf16x4 __attribute__((ext_vector_type(4)));
typedef float f32x4  __attribute__((ext_vector_type(4)));
typedef float f32x16 __attribute__((ext_vector_type(16)));

// ---------- bf16 helpers ----------
__device__ __forceinline__ float bflo(unsigned int w) { return __uint_as_float(w << 16); }
__device__ __forceinline__ float bfhi(unsigned int w) { return __uint_as_float(w & 0xffff0000u); }
__device__ __forceinline__ unsigned int f2bfbits(float f) {
    unsigned int i = __float_as_uint(f);
    return (i + 0x7fffu + ((i >> 16) & 1u)) >> 16;
}
__device__ __forceinline__ unsigned int packbf(float a, float b) {
    return f2bfbits(a) | (f2bfbits(b) << 16);
}
__device__ __forceinline__ unsigned int cvtpk_bf16(float lo, float hi) {
    unsigned int r;
    asm("v_cvt_pk_bf16_f32 %0, %1, %2" : "=v"(r) : "v"(lo), "v"(hi));
    return r;
}

// ---------- async global->LDS, 16B per lane ----------
typedef const __attribute__((address_space(1))) unsigned int* gas_t;
typedef __attribute__((address_space(3))) unsigned int* las_t;
__device__ __forceinline__ void gll16(const void* g, void* l) {
    __builtin_amdgcn_global_load_lds((gas_t)g, (las_t)l, 16, 0, 0);
}

// ---------- device bodies ----------
__device__ __forceinline__ void conv_body(const float* __restrict__ in,
                                          unsigned short* __restrict__ outp,
                                          int blk, int t)
{
    const size_t i = ((size_t)blk * 256 + t) * 8;
    const float4 f0 = *(const float4*)(in + i);
    const float4 f1 = *(const float4*)(in + i + 4);
    uint4 o;
    o.x = packbf(f0.x, f0.y); o.y = packbf(f0.z, f0.w);
    o.z = packbf(f1.x, f1.y); o.w = packbf(f1.z, f1.w);
    *(uint4*)(outp + i) = o;
}

__device__ __forceinline__ void pools_body(const float* __restrict__ v,
                                           float* __restrict__ pbuf2,
                                           int pb, int t)
{
    const int bv = pb >> 3, lc = pb & 7;
    const float* vb = v + (size_t)bv * (L_ * C_) + (size_t)lc * 32 * C_ + t * 4;
    float a0 = 0.f, a1 = 0.f, a2 = 0.f, a3 = 0.f;
#pragma unroll
    for (int l = 0; l < 32; ++l) {
        const float4 f = *(const float4*)(vb + (size_t)l * C_);
        a0 += f.x; a1 += f.y; a2 += f.z; a3 += f.w;
    }
    float4 o; o.x = a0; o.y = a1; o.z = a2; o.w = a3;
    *(float4*)(pbuf2 + ((size_t)lc * 32 + bv) * C_ + t * 4) = o;
}

__device__ __forceinline__ void wprep_body(const float* __restrict__ W,
                                           unsigned short* __restrict__ Wt,
                                           float (*tile)[65], int k0, int n0, int t)
{
    const int r = t >> 2, c4 = (t & 3) * 16;
#pragma unroll
    for (int i = 0; i < 4; ++i) {
        const float4 f = *(const float4*)(W + (size_t)(k0 + r) * C_ + n0 + c4 + i * 4);
        tile[r][c4 + i * 4 + 0] = f.x; tile[r][c4 + i * 4 + 1] = f.y;
        tile[r][c4 + i * 4 + 2] = f.z; tile[r][c4 + i * 4 + 3] = f.w;
    }
    __syncthreads();
    unsigned int ow[8];
#pragma unroll
    for (int p = 0; p < 8; ++p)
        ow[p] = packbf(tile[c4 + 2 * p][r], tile[c4 + 2 * p + 1][r]);
    unsigned short* dst = Wt + (size_t)(n0 + r) * C_ + k0 + c4;
    uint4 o0; o0.x = ow[0]; o0.y = ow[1]; o0.z = ow[2]; o0.w = ow[3];
    uint4 o1; o1.x = ow[4]; o1.y = ow[5]; o1.z = ow[6]; o1.w = ow[7];
    *(uint4*)dst = o0;
    *(uint4*)(dst + 8) = o1;
}

// ---------- standalone kernels (fallback path) ----------
__global__ __launch_bounds__(256) void conv_k(const float* __restrict__ in,
                                              unsigned short* __restrict__ outp)
{ conv_body(in, outp, blockIdx.x, threadIdx.x); }

__global__ __launch_bounds__(256) void pools_k(const float* __restrict__ v,
                                               float* __restrict__ pbuf2)
{ pools_body(v, pbuf2, blockIdx.x, threadIdx.x); }

__global__ __launch_bounds__(256) void wprep_k(const float* __restrict__ W,
                                               unsigned short* __restrict__ Wt)
{
    __shared__ float tile[64][65];
    wprep_body(W, Wt, tile, blockIdx.x * 64, blockIdx.y * 64, threadIdx.x);
}

__global__ __launch_bounds__(1024) void maskpack_k(
    const void* __restrict__ src, unsigned char* __restrict__ dst)
{
    __shared__ int v_word;
    const int t = threadIdx.x;
    if (t == 0) v_word = 1;
    __syncthreads();
    const unsigned int* s32 = (const unsigned int*)src;
    const unsigned int w = s32[t];
    if (w > 1u && w != 0x3F800000u) atomicAnd(&v_word, 0);
    __syncthreads();
    const bool word_mode = (v_word != 0);
    const unsigned char* s8 = (const unsigned char*)src;
#pragma unroll
    for (int i = 0; i < 8; ++i) {
        const int idx = t * 8 + i;
        const int bv = idx >> 8, l = idx & 255;
        unsigned int bits = 0;
#pragma unroll
        for (int o = 0; o < O_; ++o) {
            const int mi = (o * BV_ + bv) * L_ + l;
            const unsigned int m = word_mode ? (s32[mi] != 0u) : (s8[mi] != 0);
            bits |= m << o;
        }
        dst[idx] = (unsigned char)bits;
    }
}

// ---------- fused prep: 3 convs + pools + maskpack + 4 wpreps ----------
__global__ __launch_bounds__(256) void prep_k(
    const float* __restrict__ q, const float* __restrict__ k, const float* __restrict__ v,
    const void* __restrict__ msk,
    const float* __restrict__ Wq, const float* __restrict__ Wk,
    const float* __restrict__ Wv, const float* __restrict__ Wm,
    unsigned short* __restrict__ cq, unsigned short* __restrict__ ck,
    unsigned short* __restrict__ cv,
    float* __restrict__ pbuf2, unsigned char* __restrict__ mpk,
    unsigned short* __restrict__ Wtb)
{
    __shared__ float tile[64][65];
    const int blk = blockIdx.x;
    const int t = threadIdx.x;
    if (blk < 12288) {
        const int wsel = blk >> 12;
        const float* in = (wsel == 0) ? q : (wsel == 1) ? k : v;
        unsigned short* outp = (wsel == 0) ? cq : (wsel == 1) ? ck : cv;
        conv_body(in, outp, blk & 4095, t);
    } else if (blk < 12544) {
        pools_body(v, pbuf2, blk - 12288, t);
    } else if (blk < 12548) {
        __shared__ int v_word;
        if (t == 0) v_word = 1;
        __syncthreads();
        const unsigned int* s32 = (const unsigned int*)msk;
        const unsigned int w = s32[t];
        if (w > 1u && w != 0x3F800000u) atomicAnd(&v_word, 0);
        __syncthreads();
        const bool word_mode = (v_word != 0);
        const unsigned char* s8 = (const unsigned char*)msk;
        const int tt = (blk - 12544) * 256 + t;
#pragma unroll
        for (int i = 0; i < 8; ++i) {
            const int idx = tt * 8 + i;
            const int bv = idx >> 8, l = idx & 255;
            unsigned int bits = 0;
#pragma unroll
            for (int o = 0; o < O_; ++o) {
                const int mi = (o * BV_ + bv) * L_ + l;
                const unsigned int m = word_mode ? (s32[mi] != 0u) : (s8[mi] != 0);
                bits |= m << o;
            }
            mpk[idx] = (unsigned char)bits;
        }
    } else {
        const int wb = blk - 12548;
        const int wsel = wb >> 8;
        const float* W = (wsel == 0) ? Wq : (wsel == 1) ? Wk : (wsel == 2) ? Wv : Wm;
        unsigned short* Wt = Wtb + (size_t)wsel * (C_ * C_);
        const int b = wb & 255;
        wprep_body(W, Wt, tile, (b & 15) * 64, (b >> 4) * 64, t);
    }
}

// ---------- MLP layer 1 (pool partial-sum folded in), split-k 32 chunks ----------
// pooled[b][c] recomputed inline from pbuf2 (L2-resident 128 KB): same
// summation order as the old poolr_k (p=0..7 then *1/256) -> bit-identical.
__global__ __launch_bounds__(256) void mlp1_k(const float* __restrict__ pbuf2,
                                              const float* __restrict__ W1,
                                              float* __restrict__ pbuf)
{
    const int t = threadIdx.x;
    const int col = blockIdx.x * 32 + (t & 31);
    const int b0 = (t >> 5) * 4;
    const int c0 = blockIdx.y * 32;
    float a0 = 0.f, a1 = 0.f, a2 = 0.f, a3 = 0.f;
#pragma unroll
    for (int c = c0; c < c0 + 32; ++c) {
        const float wv = W1[(size_t)c * 512 + col];
        float p0 = 0.f, p1 = 0.f, p2 = 0.f, p3 = 0.f;
#pragma unroll
        for (int p = 0; p < 8; ++p) {
            const float* pb = pbuf2 + (size_t)p * (32 * C_) + c;
            p0 += pb[(size_t)(b0 + 0) * C_];
            p1 += pb[(size_t)(b0 + 1) * C_];
            p2 += pb[(size_t)(b0 + 2) * C_];
            p3 += pb[(size_t)(b0 + 3) * C_];
        }
        const float inv = 1.0f / 256.0f;
        a0 = fmaf(p0 * inv, wv, a0);
        a1 = fmaf(p1 * inv, wv, a1);
        a2 = fmaf(p2 * inv, wv, a2);
        a3 = fmaf(p3 * inv, wv, a3);
    }
    const size_t pb = ((size_t)blockIdx.y * 32 + b0) * 512 + col;
    pbuf[pb]        = a0;
    pbuf[pb + 512]  = a1;
    pbuf[pb + 1024] = a2;
    pbuf[pb + 1536] = a3;
}

// ---------- MLP layer 2 + gumbel softmax ----------
__global__ __launch_bounds__(256) void mlp2_k(const float* __restrict__ pbuf,
                                              const float* __restrict__ W2,
                                              const float* __restrict__ b2,
                                              const float* __restrict__ gum,
                                              const float* __restrict__ tau,
                                              float* __restrict__ alphas)
{
    __shared__ float red[4][O_];
    const int bv = blockIdx.x, t = threadIdx.x;
    float h0 = 0.f, h1 = 0.f;
#pragma unroll
    for (int ch = 0; ch < 32; ++ch) {
        h0 += pbuf[((size_t)ch * 32 + bv) * 512 + t];
        h1 += pbuf[((size_t)ch * 32 + bv) * 512 + 256 + t];
    }
    h0 = fmaxf(h0, 0.f); h1 = fmaxf(h1, 0.f);
    float part[O_];
#pragma unroll
    for (int o = 0; o < O_; ++o)
        part[o] = h0 * W2[t * O_ + o] + h1 * W2[(t + 256) * O_ + o];
#pragma unroll
    for (int off = 32; off >= 1; off >>= 1) {
#pragma unroll
        for (int o = 0; o < O_; ++o) part[o] += __shfl_down(part[o], off, 64);
    }
    const int wid = t >> 6, lane = t & 63;
    if (lane == 0) {
#pragma unroll
        for (int o = 0; o < O_; ++o) red[wid][o] = part[o];
    }
    __syncthreads();
    if (t == 0) {
        float lg[O_];
#pragma unroll
        for (int o = 0; o < O_; ++o)
            lg[o] = red[0][o] + red[1][o] + red[2][o] + red[3][o] + b2[o];
        float mx = fmaxf(fmaxf(lg[0], lg[1]), fmaxf(lg[2], lg[3]));
        float s = 0.f;
#pragma unroll
        for (int o = 0; o < O_; ++o) s += expf(lg[o] - mx);
        const float lse = logf(s) + mx;
        const float it = 1.0f / tau[0];
        float y[O_];
#pragma unroll
        for (int o = 0; o < O_; ++o) y[o] = (lg[o] - lse + gum[bv * O_ + o]) * it;
        float my = fmaxf(fmaxf(y[0], y[1]), fmaxf(y[2], y[3]));
        float z = 0.f;
#pragma unroll
        for (int o = 0; o < O_; ++o) { y[o] = expf(y[o] - my); z += y[o]; }
        const float iz = 1.0f / z;
#pragma unroll
        for (int o = 0; o < O_; ++o) alphas[bv * O_ + o] = y[o] * iz;
    }
}

// ---------- MFMA bf16 GEMM body: BK=64, 2-deep dbuf, STATIC buffers ----------
// (round-16 config: counted vmcnt(8), raw barriers, 8-slot XOR swizzle both sides)
template <bool PROJSTORE>
__device__ __forceinline__ void mgemm_body(
    const unsigned short* __restrict__ Ab, const unsigned short* __restrict__ Wt,
    const float* __restrict__ bias, void* __restrict__ out_, int n0, int m0)
{
    __shared__ unsigned short As0[128][64], As1[128][64];   // 4 x 16 KB
    __shared__ unsigned short Bs0[128][64], Bs1[128][64];
    const int t = threadIdx.x;
    const int w = t >> 6, lane = t & 63;
    const int wm = (w >> 1) * 64, wn = (w & 1) * 64;
    const int fr = lane & 15;
    const int fq = lane >> 4;

    const int sr = w * 8 + (lane >> 3);                       // +i*32
    const int sc = ((lane & 7) ^ ((lane >> 3) & 7)) * 8;      // pre-swizzled src col
    const unsigned short* aP = Ab + (size_t)(m0 + sr) * C_ + sc;
    const unsigned short* bP = Wt + (size_t)(n0 + sr) * C_ + sc;

    const int frm = (fr & 7);   // read-side swizzle key (row&7 == fr&7)

    f32x4 acc[4][4] = {};

#define STAGE(AB, BB, KT)                                                   \
    {                                                                       \
        _Pragma("unroll")                                                   \
        for (int i_ = 0; i_ < 4; ++i_) {                                    \
            gll16(aP + (size_t)i_ * 32 * C_ + (KT), &AB[i_ * 32 + w * 8][0]);\
            gll16(bP + (size_t)i_ * 32 * C_ + (KT), &BB[i_ * 32 + w * 8][0]);\
        }                                                                   \
    }

#define COMPUTE(AB, BB)                                                     \
    {                                                                       \
        _Pragma("unroll")                                                   \
        for (int c_ = 0; c_ < 2; ++c_) {                                    \
            const int rk_ = ((c_ * 4 + fq) ^ frm) * 8;                      \
            bf16x8 af_[4], bf_[4];                                          \
            _Pragma("unroll")                                               \
            for (int i_ = 0; i_ < 4; ++i_)                                  \
                af_[i_] = *(const bf16x8*)&AB[wm + i_ * 16 + fr][rk_];      \
            _Pragma("unroll")                                               \
            for (int j_ = 0; j_ < 4; ++j_)                                  \
                bf_[j_] = *(const bf16x8*)&BB[wn + j_ * 16 + fr][rk_];      \
            _Pragma("unroll")                                               \
            for (int i_ = 0; i_ < 4; ++i_)                                  \
                _Pragma("unroll")                                           \
                for (int j_ = 0; j_ < 4; ++j_)                              \
                    acc[i_][j_] = __builtin_amdgcn_mfma_f32_16x16x32_bf16(  \
                        af_[i_], bf_[j_], acc[i_][j_], 0, 0, 0);            \
        }                                                                   \
    }

    STAGE(As0, Bs0, 0);                       // prologue: tile 0 -> buf0
#pragma unroll 1
    for (int kt = 0; kt < C_; kt += 128) {
        STAGE(As1, Bs1, kt + 64);             // prefetch tile kt+64 -> buf1
        asm volatile("s_waitcnt vmcnt(8)" ::: "memory");   // tile kt done
        __builtin_amdgcn_s_barrier();
        COMPUTE(As0, Bs0);                    // compute tile kt
        __builtin_amdgcn_s_barrier();         // buf0 free
        if (kt + 128 < C_) {
            STAGE(As0, Bs0, kt + 128);        // prefetch tile kt+128 -> buf0
            asm volatile("s_waitcnt vmcnt(8)" ::: "memory");  // tile kt+64 done
        } else {
            asm volatile("s_waitcnt vmcnt(0)" ::: "memory");
        }
        __builtin_amdgcn_s_barrier();
        COMPUTE(As1, Bs1);                    // compute tile kt+64
        __builtin_amdgcn_s_barrier();         // buf1 free
    }
#undef STAGE
#undef COMPUTE

#pragma unroll
    for (int j = 0; j < 4; ++j) {
        const int gcol = n0 + wn + j * 16 + fr;
        const float bj = bias[gcol];
#pragma unroll
        for (int i = 0; i < 4; ++i) {
#pragma unroll
            for (int r = 0; r < 4; ++r) {
                const int grow = m0 + wm + i * 16 + fq * 4 + r;
                const float val = acc[i][j][r] + bj;
                if (PROJSTORE) {
                    const int bvb = grow >> 8, l = grow & 255;
                    const int hh = gcol >> 6, dh = gcol & 63;
                    ((unsigned short*)out_)[(((size_t)bvb * H_ + hh) * L_ + l) * DH_ + dh] =
                        (unsigned short)f2bfbits(val);
                } else {
                    ((float*)out_)[(size_t)grow * C_ + gcol] = val;
                }
            }
        }
    }
}

template <bool PROJSTORE>
__global__ __launch_bounds__(256) void mgemm_k(
    const unsigned short* __restrict__ Ab, const unsigned short* __restrict__ Wt,
    const float* __restrict__ bias, void* __restrict__ out_)
{
    mgemm_body<PROJSTORE>(Ab, Wt, bias, out_, blockIdx.x * 128, blockIdx.y * 128);
}

// three projection GEMMs, one launch, XCD-chunked
__global__ __launch_bounds__(256) void mgemm3_k(
    const unsigned short* __restrict__ cq, const unsigned short* __restrict__ ck,
    const unsigned short* __restrict__ cv, const unsigned short* __restrict__ Wtb,
    const float* __restrict__ bq, const float* __restrict__ bk, const float* __restrict__ bvv,
    unsigned short* __restrict__ qqw, unsigned short* __restrict__ kkw,
    unsigned short* __restrict__ vvw)
{
    const int b = blockIdx.x;
    const int swz = (b & 7) * 192 + (b >> 3);   // bijective: 1536 = 8*192
    const int which = swz >> 9;
    const int g = swz & 511;
    const unsigned short* A = (which == 0) ? cq : (which == 1) ? ck : cv;
    const unsigned short* W = Wtb + (size_t)which * (C_ * C_);
    const float* bias = (which == 0) ? bq : (which == 1) ? bk : bvv;
    unsigned short* outp = (which == 0) ? qqw : (which == 1) ? kkw : vvw;
    mgemm_body<true>(A, W, bias, (void*)outp, (g & 7) * 128, (g >> 3) * 128);
}

// final GEMM, 1D 512 blocks, XCD-chunked (cpx = 64)
__global__ __launch_bounds__(256) void mgemmf_k(
    const unsigned short* __restrict__ Ab, const unsigned short* __restrict__ Wt,
    const float* __restrict__ bias, float* __restrict__ out_)
{
    const int b = blockIdx.x;
    const int swz = (b & 7) * 64 + (b >> 3);    // bijective: 512 = 8*64
    mgemm_body<false>(Ab, Wt, bias, (void*)out_, (swz & 7) * 128, (swz >> 3) * 128);
}

// ---------- fused attention (round-15 verified) ----------
__global__ __launch_bounds__(256) void attn_k(
    const unsigned short* __restrict__ qq, const unsigned short* __restrict__ kk,
    const unsigned short* __restrict__ vv, const unsigned char* __restrict__ mpk,
    const float* __restrict__ alphas, unsigned short* __restrict__ atted)
{
    __shared__ unsigned short Vt[DH_][260];
    __shared__ unsigned int mkw[64];
    __shared__ float al[O_];
    const int h = blockIdx.x, bv = blockIdx.y;
    const int t = threadIdx.x;
    const int w = t >> 6, lane = t & 63;
    const int fr = lane & 31, hf = lane >> 5;
    const size_t hb = ((size_t)bv * H_ + h) * (L_ * DH_);

    {   // stage V row t transposed into Vt[:][t]
        const uint4* gv = (const uint4*)(vv + hb + (size_t)t * DH_);
#pragma unroll
        for (int i = 0; i < 8; ++i) {
            const uint4 wv = gv[i];
            const unsigned int ws4[4] = {wv.x, wv.y, wv.z, wv.w};
#pragma unroll
            for (int jd = 0; jd < 4; ++jd) {
                Vt[i * 8 + jd * 2 + 0][t] = (unsigned short)(ws4[jd] & 0xffffu);
                Vt[i * 8 + jd * 2 + 1][t] = (unsigned short)(ws4[jd] >> 16);
            }
        }
    }
    if (t < 64) mkw[t] = ((const unsigned int*)mpk)[bv * 64 + t];
    if (t < O_) al[t] = alphas[bv * O_ + t];
    __syncthreads();
    const float al0 = al[0], al1 = al[1], al2 = al[2], al3 = al[3];

#pragma unroll 1
    for (int qt = 0; qt < 2; ++qt) {
        const int q32 = w * 64 + qt * 32;
        bf16x8 qf[4];
#pragma unroll
        for (int st = 0; st < 4; ++st)
            qf[st] = *(const bf16x8*)(qq + hb + (size_t)(q32 + fr) * DH_ + st * 16 + hf * 8);

        // ---- pass 1: masked T sums ----
        float T0 = 0.f, T1 = 0.f, T2 = 0.f, T3 = 0.f;
#pragma unroll 1
        for (int j = 0; j < 8; ++j) {
            bf16x8 kf[4];
#pragma unroll
            for (int st = 0; st < 4; ++st)
                kf[st] = *(const bf16x8*)(kk + hb + (size_t)(j * 32 + fr) * DH_ + st * 16 + hf * 8);
            f32x16 s = {};
#pragma unroll
            for (int st = 0; st < 4; ++st)
                s = __builtin_amdgcn_mfma_f32_32x32x16_bf16(kf[st], qf[st], s, 0, 0, 0);
#pragma unroll
            for (int c = 0; c < 4; ++c) {
                const unsigned int iv = (~mkw[j * 8 + c * 2 + hf]) & 0x0F0F0F0Fu;
#pragma unroll
                for (int r = 0; r < 4; ++r) {
                    const float e = __expf(s[c * 4 + r] * 0.125f);
                    const unsigned int nib = iv >> (r * 8);
                    T0 = fmaf(e, (float)( nib       & 1u), T0);
                    T1 = fmaf(e, (float)((nib >> 1) & 1u), T1);
                    T2 = fmaf(e, (float)((nib >> 2) & 1u), T2);
                    T3 = fmaf(e, (float)((nib >> 3) & 1u), T3);
                }
            }
        }
        T0 += __shfl_xor(T0, 32, 64);
        T1 += __shfl_xor(T1, 32, 64);
        T2 += __shfl_xor(T2, 32, 64);
        T3 += __shfl_xor(T3, 32, 64);
        const float c0 = al0 * __builtin_amdgcn_rcpf(fmaxf(T0, 1e-30f));
        const float c1 = al1 * __builtin_amdgcn_rcpf(fmaxf(T1, 1e-30f));
        const float c2 = al2 * __builtin_amdgcn_rcpf(fmaxf(T2, 1e-30f));
        const float c3 = al3 * __builtin_amdgcn_rcpf(fmaxf(T3, 1e-30f));

        // ---- pass 2: recompute S, weight, PV ----
        f32x16 o0 = {};
        f32x16 o1 = {};
#pragma unroll 1
        for (int j = 0; j < 8; ++j) {
            bf16x8 kf[4];
#pragma unroll
            for (int st = 0; st < 4; ++st)
                kf[st] = *(const bf16x8*)(kk + hb + (size_t)(j * 32 + fr) * DH_ + st * 16 + hf * 8);
            f32x16 s = {};
#pragma unroll
            for (int st = 0; st < 4; ++st)
                s = __builtin_amdgcn_mfma_f32_32x32x16_bf16(kf[st], qf[st], s, 0, 0, 0);

            unsigned int pe[4][2];
#pragma unroll
            for (int c = 0; c < 4; ++c) {
                const unsigned int iv = (~mkw[j * 8 + c * 2 + hf]) & 0x0F0F0F0Fu;
                float p[4];
#pragma unroll
                for (int r = 0; r < 4; ++r) {
                    const float e = __expf(s[c * 4 + r] * 0.125f);
                    const unsigned int nib = iv >> (r * 8);
                    float cf =      c0 * (float)( nib       & 1u);
                    cf = fmaf(c1, (float)((nib >> 1) & 1u), cf);
                    cf = fmaf(c2, (float)((nib >> 2) & 1u), cf);
                    cf = fmaf(c3, (float)((nib >> 3) & 1u), cf);
                    p[r] = e * cf;
                }
                pe[c][0] = cvtpk_bf16(p[0], p[1]);
                pe[c][1] = cvtpk_bf16(p[2], p[3]);
            }
#pragma unroll
            for (int b = 0; b < 2; ++b) {
                const unsigned int qe0 = pe[2 * b][0],     qe1 = pe[2 * b][1];
                const unsigned int qo0 = pe[2 * b + 1][0], qo1 = pe[2 * b + 1][1];
                const unsigned int xe0 = (unsigned int)__shfl_xor((int)qe0, 32, 64);
                const unsigned int xe1 = (unsigned int)__shfl_xor((int)qe1, 32, 64);
                const unsigned int xo0 = (unsigned int)__shfl_xor((int)qo0, 32, 64);
                const unsigned int xo1 = (unsigned int)__shfl_xor((int)qo1, 32, 64);
                union { unsigned int d[4]; bf16x8 v; } pa;
                pa.d[0] = hf ? xo0 : qe0;
                pa.d[1] = hf ? xo1 : qe1;
                pa.d[2] = hf ? qo0 : xe0;
                pa.d[3] = hf ? qo1 : xe1;

                const int kc = j * 32 + b * 16 + hf * 8;
                union { struct { bf16x4 lo, hi; } p2; bf16x8 v; } v0u, v1u;
                v0u.p2.lo = *(const bf16x4*)&Vt[ 0 + fr][kc];
                v0u.p2.hi = *(const bf16x4*)&Vt[ 0 + fr][kc + 4];
                v1u.p2.lo = *(const bf16x4*)&Vt[32 + fr][kc];
                v1u.p2.hi = *(const bf16x4*)&Vt[32 + fr][kc + 4];
                o0 = __builtin_amdgcn_mfma_f32_32x32x16_bf16(pa.v, v0u.v, o0, 0, 0, 0);
                o1 = __builtin_amdgcn_mfma_f32_32x32x16_bf16(pa.v, v1u.v, o1, 0, 0, 0);
            }
        }
#pragma unroll
        for (int reg = 0; reg < 16; ++reg) {
            const int qrow = q32 + (reg & 3) + 8 * (reg >> 2) + 4 * hf;
            unsigned short* dst = atted + ((size_t)bv * L_ + qrow) * C_ + h * DH_;
            dst[fr]      = (unsigned short)f2bfbits(o0[reg]);
            dst[32 + fr] = (unsigned short)f2bfbits(o1[reg]);
        }
    }
}

// ---------- launch ----------
extern "C" void kernel_launch(void* const* d_in, const int* in_sizes, int n_in,
                              void* d_out, int out_size, void* d_ws, size_t ws_size,
                              hipStream_t stream)
{
    (void)in_sizes; (void)n_in; (void)out_size;
    const float* v   = (const float*)d_in[0];
    const float* k   = (const float*)d_in[1];
    const float* q   = (const float*)d_in[2];
    const void*  msk = d_in[3];
    const float* tau = (const float*)d_in[4];
    const float* gum = (const float*)d_in[6];
    const float* Wv  = (const float*)d_in[7];
    const float* bvp = (const float*)d_in[8];
    const float* Wk  = (const float*)d_in[9];
    const float* bkp = (const float*)d_in[10];
    const float* Wq  = (const float*)d_in[11];
    const float* bqp = (const float*)d_in[12];
    const float* Wm  = (const float*)d_in[13];
    const float* bmp = (const float*)d_in[14];
    const float* W1  = (const float*)d_in[15];
    const float* W2  = (const float*)d_in[16];
    const float* b2  = (const float*)d_in[17];
    float* out = (float*)d_out;

    char* ws = (char*)d_ws;

    if (ws_size >= (size_t)128 * MB_) {
        float* alphas       = (float*)ws;
        unsigned char* mpk  = (unsigned char*)(ws + 1024);
        float* pbuf2        = (float*)(ws + 147456);
        float* pbuf         = (float*)(ws + 1196032);
        unsigned short* Wtb = (unsigned short*)(ws + (size_t)4 * MB_);   // 4 x 2 MB
        unsigned short* cq  = (unsigned short*)(ws + (size_t)14 * MB_);  // 16 MB each
        unsigned short* ck  = (unsigned short*)(ws + (size_t)30 * MB_);
        unsigned short* cv  = (unsigned short*)(ws + (size_t)46 * MB_);
        unsigned short* qqw = (unsigned short*)(ws + (size_t)62 * MB_);
        unsigned short* kkw = (unsigned short*)(ws + (size_t)78 * MB_);
        unsigned short* vvw = (unsigned short*)(ws + (size_t)94 * MB_);
        unsigned short* atw = (unsigned short*)(ws + (size_t)110 * MB_);

        hipLaunchKernelGGL(prep_k, dim3(13572), dim3(256), 0, stream,
                           q, k, v, msk, Wq, Wk, Wv, Wm, cq, ck, cv, pbuf2, mpk, Wtb);
        hipLaunchKernelGGL(mlp1_k, dim3(16, 32), dim3(256), 0, stream, pbuf2, W1, pbuf);
        hipLaunchKernelGGL(mlp2_k, dim3(BV_), dim3(256), 0, stream,
                           pbuf, W2, b2, gum, tau, alphas);
        hipLaunchKernelGGL(mgemm3_k, dim3(1536), dim3(256), 0, stream,
                           cq, ck, cv, Wtb, bqp, bkp, bvp, qqw, kkw, vvw);
        hipLaunchKernelGGL(attn_k, dim3(H_, BV_), dim3(256), 0, stream,
                           qqw, kkw, vvw, mpk, alphas, atw);
        hipLaunchKernelGGL(mgemmf_k, dim3(512), dim3(256), 0, stream,
                           atw, Wtb + (size_t)3 * (C_ * C_), bmp, out);
    } else {
        // fallback: serial layout (66 MB)
        float* alphas       = (float*)ws;
        unsigned char* mpk  = (unsigned char*)(ws + 1024);
        float* pbuf2        = (float*)(ws + 147456);
        float* pbuf         = (float*)(ws + 1196032);
        unsigned short* Wt  = (unsigned short*)(ws + 16384);
        unsigned short* qqw = (unsigned short*)(ws + 2113536);
        unsigned short* kkw = qqw + (size_t)M_ * C_;
        unsigned short* vvw = kkw + (size_t)M_ * C_;
        unsigned short* atw = vvw + (size_t)M_ * C_;

        hipLaunchKernelGGL(pools_k, dim3(256), dim3(256), 0, stream, v, pbuf2);
        hipLaunchKernelGGL(mlp1_k, dim3(16, 32), dim3(256), 0, stream, pbuf2, W1, pbuf);
        hipLaunchKernelGGL(mlp2_k, dim3(BV_), dim3(256), 0, stream,
                           pbuf, W2, b2, gum, tau, alphas);
        hipLaunchKernelGGL(maskpack_k, dim3(1), dim3(1024), 0, stream, msk, mpk);

        hipLaunchKernelGGL(conv_k, dim3(4096), dim3(256), 0, stream, q, atw);
        hipLaunchKernelGGL(wprep_k, dim3(16, 16), dim3(256), 0, stream, Wq, Wt);
        hipLaunchKernelGGL((mgemm_k<true>), dim3(8, 64), dim3(256), 0, stream,
                           atw, Wt, bqp, (void*)qqw);
        hipLaunchKernelGGL(conv_k, dim3(4096), dim3(256), 0, stream, k, atw);
        hipLaunchKernelGGL(wprep_k, dim3(16, 16), dim3(256), 0, stream, Wk, Wt);
        hipLaunchKernelGGL((mgemm_k<true>), dim3(8, 64), dim3(256), 0, stream,
                           atw, Wt, bkp, (void*)kkw);
        hipLaunchKernelGGL(conv_k, dim3(4096), dim3(256), 0, stream, v, atw);
        hipLaunchKernelGGL(wprep_k, dim3(16, 16), dim3(256), 0, stream, Wv, Wt);
        hipLaunchKernelGGL((mgemm_k<true>), dim3(8, 64), dim3(256), 0, stream,
                           atw, Wt, bvp, (void*)vvw);

        hipLaunchKernelGGL(attn_k, dim3(H_, BV_), dim3(256), 0, stream,
                           qqw, kkw, vvw, mpk, alphas, atw);

        hipLaunchKernelGGL(wprep_k, dim3(16, 16), dim3(256), 0, stream, Wm, Wt);
        hipLaunchKernelGGL((mgemm_k<false>), dim3(8, 64), dim3(256), 0, stream,
                           atw, Wt, bmp, (void*)out);
    }
}

// Round 20
// 183.010 us; speedup vs baseline: 1.0891x; 1.0891x over previous
//
#include <hip/hip_runtime.h>

// Problem constants
#define B_   4
#define V_   8
#define L_   256
#define C_   1024
#define H_   16
#define O_   4
#define DH_  64
#define BV_  32      // B*V
#define M_   8192    // B*V*L
#define MB_  (1024 * 1024)

typedef short bf16x8 __attribute__((ext_vector_type(8)));
typedef short bf16x4 __attribute__((ext_vector_type(4)));
typedef float f32x4  __attribute__((ext_vector_type(4)));
typedef float f32x16 __attribute__((ext_vector_type(16)));

// ---------- bf16 helpers ----------
__device__ __forceinline__ float bflo(unsigned int w) { return __uint_as_float(w << 16); }
__device__ __forceinline__ float bfhi(unsigned int w) { return __uint_as_float(w & 0xffff0000u); }
__device__ __forceinline__ unsigned int f2bfbits(float f) {
    unsigned int i = __float_as_uint(f);
    return (i + 0x7fffu + ((i >> 16) & 1u)) >> 16;
}
__device__ __forceinline__ unsigned int packbf(float a, float b) {
    return f2bfbits(a) | (f2bfbits(b) << 16);
}
__device__ __forceinline__ unsigned int cvtpk_bf16(float lo, float hi) {
    unsigned int r;
    asm("v_cvt_pk_bf16_f32 %0, %1, %2" : "=v"(r) : "v"(lo), "v"(hi));
    return r;
}

// ---------- async global->LDS, 16B per lane ----------
typedef const __attribute__((address_space(1))) unsigned int* gas_t;
typedef __attribute__((address_space(3))) unsigned int* las_t;
__device__ __forceinline__ void gll16(const void* g, void* l) {
    __builtin_amdgcn_global_load_lds((gas_t)g, (las_t)l, 16, 0, 0);
}

// ---------- device bodies ----------
__device__ __forceinline__ void conv_body(const float* __restrict__ in,
                                          unsigned short* __restrict__ outp,
                                          int blk, int t)
{
    const size_t i = ((size_t)blk * 256 + t) * 8;
    const float4 f0 = *(const float4*)(in + i);
    const float4 f1 = *(const float4*)(in + i + 4);
    uint4 o;
    o.x = packbf(f0.x, f0.y); o.y = packbf(f0.z, f0.w);
    o.z = packbf(f1.x, f1.y); o.w = packbf(f1.z, f1.w);
    *(uint4*)(outp + i) = o;
}

__device__ __forceinline__ void pools_body(const float* __restrict__ v,
                                           float* __restrict__ pbuf2,
                                           int pb, int t)
{
    const int bv = pb >> 3, lc = pb & 7;
    const float* vb = v + (size_t)bv * (L_ * C_) + (size_t)lc * 32 * C_ + t * 4;
    float a0 = 0.f, a1 = 0.f, a2 = 0.f, a3 = 0.f;
#pragma unroll
    for (int l = 0; l < 32; ++l) {
        const float4 f = *(const float4*)(vb + (size_t)l * C_);
        a0 += f.x; a1 += f.y; a2 += f.z; a3 += f.w;
    }
    float4 o; o.x = a0; o.y = a1; o.z = a2; o.w = a3;
    *(float4*)(pbuf2 + ((size_t)lc * 32 + bv) * C_ + t * 4) = o;
}

__device__ __forceinline__ void wprep_body(const float* __restrict__ W,
                                           unsigned short* __restrict__ Wt,
                                           float (*tile)[65], int k0, int n0, int t)
{
    const int r = t >> 2, c4 = (t & 3) * 16;
#pragma unroll
    for (int i = 0; i < 4; ++i) {
        const float4 f = *(const float4*)(W + (size_t)(k0 + r) * C_ + n0 + c4 + i * 4);
        tile[r][c4 + i * 4 + 0] = f.x; tile[r][c4 + i * 4 + 1] = f.y;
        tile[r][c4 + i * 4 + 2] = f.z; tile[r][c4 + i * 4 + 3] = f.w;
    }
    __syncthreads();
    unsigned int ow[8];
#pragma unroll
    for (int p = 0; p < 8; ++p)
        ow[p] = packbf(tile[c4 + 2 * p][r], tile[c4 + 2 * p + 1][r]);
    unsigned short* dst = Wt + (size_t)(n0 + r) * C_ + k0 + c4;
    uint4 o0; o0.x = ow[0]; o0.y = ow[1]; o0.z = ow[2]; o0.w = ow[3];
    uint4 o1; o1.x = ow[4]; o1.y = ow[5]; o1.z = ow[6]; o1.w = ow[7];
    *(uint4*)dst = o0;
    *(uint4*)(dst + 8) = o1;
}

// ---------- standalone kernels (fallback path) ----------
__global__ __launch_bounds__(256) void conv_k(const float* __restrict__ in,
                                              unsigned short* __restrict__ outp)
{ conv_body(in, outp, blockIdx.x, threadIdx.x); }

__global__ __launch_bounds__(256) void pools_k(const float* __restrict__ v,
                                               float* __restrict__ pbuf2)
{ pools_body(v, pbuf2, blockIdx.x, threadIdx.x); }

__global__ __launch_bounds__(256) void wprep_k(const float* __restrict__ W,
                                               unsigned short* __restrict__ Wt)
{
    __shared__ float tile[64][65];
    wprep_body(W, Wt, tile, blockIdx.x * 64, blockIdx.y * 64, threadIdx.x);
}

__global__ __launch_bounds__(1024) void maskpack_k(
    const void* __restrict__ src, unsigned char* __restrict__ dst)
{
    __shared__ int v_word;
    const int t = threadIdx.x;
    if (t == 0) v_word = 1;
    __syncthreads();
    const unsigned int* s32 = (const unsigned int*)src;
    const unsigned int w = s32[t];
    if (w > 1u && w != 0x3F800000u) atomicAnd(&v_word, 0);
    __syncthreads();
    const bool word_mode = (v_word != 0);
    const unsigned char* s8 = (const unsigned char*)src;
#pragma unroll
    for (int i = 0; i < 8; ++i) {
        const int idx = t * 8 + i;
        const int bv = idx >> 8, l = idx & 255;
        unsigned int bits = 0;
#pragma unroll
        for (int o = 0; o < O_; ++o) {
            const int mi = (o * BV_ + bv) * L_ + l;
            const unsigned int m = word_mode ? (s32[mi] != 0u) : (s8[mi] != 0);
            bits |= m << o;
        }
        dst[idx] = (unsigned char)bits;
    }
}

// ---------- fused prep: 3 convs + pools + maskpack + 4 wpreps ----------
__global__ __launch_bounds__(256) void prep_k(
    const float* __restrict__ q, const float* __restrict__ k, const float* __restrict__ v,
    const void* __restrict__ msk,
    const float* __restrict__ Wq, const float* __restrict__ Wk,
    const float* __restrict__ Wv, const float* __restrict__ Wm,
    unsigned short* __restrict__ cq, unsigned short* __restrict__ ck,
    unsigned short* __restrict__ cv,
    float* __restrict__ pbuf2, unsigned char* __restrict__ mpk,
    unsigned short* __restrict__ Wtb)
{
    __shared__ float tile[64][65];
    const int blk = blockIdx.x;
    const int t = threadIdx.x;
    if (blk < 12288) {
        const int wsel = blk >> 12;
        const float* in = (wsel == 0) ? q : (wsel == 1) ? k : v;
        unsigned short* outp = (wsel == 0) ? cq : (wsel == 1) ? ck : cv;
        conv_body(in, outp, blk & 4095, t);
    } else if (blk < 12544) {
        pools_body(v, pbuf2, blk - 12288, t);
    } else if (blk < 12548) {
        __shared__ int v_word;
        if (t == 0) v_word = 1;
        __syncthreads();
        const unsigned int* s32 = (const unsigned int*)msk;
        const unsigned int w = s32[t];
        if (w > 1u && w != 0x3F800000u) atomicAnd(&v_word, 0);
        __syncthreads();
        const bool word_mode = (v_word != 0);
        const unsigned char* s8 = (const unsigned char*)msk;
        const int tt = (blk - 12544) * 256 + t;
#pragma unroll
        for (int i = 0; i < 8; ++i) {
            const int idx = tt * 8 + i;
            const int bv = idx >> 8, l = idx & 255;
            unsigned int bits = 0;
#pragma unroll
            for (int o = 0; o < O_; ++o) {
                const int mi = (o * BV_ + bv) * L_ + l;
                const unsigned int m = word_mode ? (s32[mi] != 0u) : (s8[mi] != 0);
                bits |= m << o;
            }
            mpk[idx] = (unsigned char)bits;
        }
    } else {
        const int wb = blk - 12548;
        const int wsel = wb >> 8;
        const float* W = (wsel == 0) ? Wq : (wsel == 1) ? Wk : (wsel == 2) ? Wv : Wm;
        unsigned short* Wt = Wtb + (size_t)wsel * (C_ * C_);
        const int b = wb & 255;
        wprep_body(W, Wt, tile, (b & 15) * 64, (b >> 4) * 64, t);
    }
}

// ---------- pooling stage 2 ----------
__global__ __launch_bounds__(256) void poolr_k(const float* __restrict__ pbuf2,
                                               float* __restrict__ pooled)
{
    const int idx = blockIdx.x * 256 + threadIdx.x;
    float s = 0.f;
#pragma unroll
    for (int p = 0; p < 8; ++p) s += pbuf2[(size_t)p * (32 * C_) + idx];
    pooled[idx] = s * (1.0f / 256.0f);
}

// ---------- MLP layer 1, split-k 32 chunks ----------
__global__ __launch_bounds__(256) void mlp1_k(const float* __restrict__ pooled,
                                              const float* __restrict__ W1,
                                              float* __restrict__ pbuf)
{
    const int t = threadIdx.x;
    const int col = blockIdx.x * 32 + (t & 31);
    const int b0 = (t >> 5) * 4;
    const int c0 = blockIdx.y * 32;
    float a0 = 0.f, a1 = 0.f, a2 = 0.f, a3 = 0.f;
#pragma unroll
    for (int c = c0; c < c0 + 32; ++c) {
        const float wv = W1[(size_t)c * 512 + col];
        a0 = fmaf(pooled[(size_t)(b0 + 0) * C_ + c], wv, a0);
        a1 = fmaf(pooled[(size_t)(b0 + 1) * C_ + c], wv, a1);
        a2 = fmaf(pooled[(size_t)(b0 + 2) * C_ + c], wv, a2);
        a3 = fmaf(pooled[(size_t)(b0 + 3) * C_ + c], wv, a3);
    }
    const size_t pb = ((size_t)blockIdx.y * 32 + b0) * 512 + col;
    pbuf[pb]        = a0;
    pbuf[pb + 512]  = a1;
    pbuf[pb + 1024] = a2;
    pbuf[pb + 1536] = a3;
}

// ---------- MLP layer 2 + gumbel softmax ----------
__global__ __launch_bounds__(256) void mlp2_k(const float* __restrict__ pbuf,
                                              const float* __restrict__ W2,
                                              const float* __restrict__ b2,
                                              const float* __restrict__ gum,
                                              const float* __restrict__ tau,
                                              float* __restrict__ alphas)
{
    __shared__ float red[4][O_];
    const int bv = blockIdx.x, t = threadIdx.x;
    float h0 = 0.f, h1 = 0.f;
#pragma unroll
    for (int ch = 0; ch < 32; ++ch) {
        h0 += pbuf[((size_t)ch * 32 + bv) * 512 + t];
        h1 += pbuf[((size_t)ch * 32 + bv) * 512 + 256 + t];
    }
    h0 = fmaxf(h0, 0.f); h1 = fmaxf(h1, 0.f);
    float part[O_];
#pragma unroll
    for (int o = 0; o < O_; ++o)
        part[o] = h0 * W2[t * O_ + o] + h1 * W2[(t + 256) * O_ + o];
#pragma unroll
    for (int off = 32; off >= 1; off >>= 1) {
#pragma unroll
        for (int o = 0; o < O_; ++o) part[o] += __shfl_down(part[o], off, 64);
    }
    const int wid = t >> 6, lane = t & 63;
    if (lane == 0) {
#pragma unroll
        for (int o = 0; o < O_; ++o) red[wid][o] = part[o];
    }
    __syncthreads();
    if (t == 0) {
        float lg[O_];
#pragma unroll
        for (int o = 0; o < O_; ++o)
            lg[o] = red[0][o] + red[1][o] + red[2][o] + red[3][o] + b2[o];
        float mx = fmaxf(fmaxf(lg[0], lg[1]), fmaxf(lg[2], lg[3]));
        float s = 0.f;
#pragma unroll
        for (int o = 0; o < O_; ++o) s += expf(lg[o] - mx);
        const float lse = logf(s) + mx;
        const float it = 1.0f / tau[0];
        float y[O_];
#pragma unroll
        for (int o = 0; o < O_; ++o) y[o] = (lg[o] - lse + gum[bv * O_ + o]) * it;
        float my = fmaxf(fmaxf(y[0], y[1]), fmaxf(y[2], y[3]));
        float z = 0.f;
#pragma unroll
        for (int o = 0; o < O_; ++o) { y[o] = expf(y[o] - my); z += y[o]; }
        const float iz = 1.0f / z;
#pragma unroll
        for (int o = 0; o < O_; ++o) alphas[bv * O_ + o] = y[o] * iz;
    }
}

// ---------- MFMA bf16 GEMM body: BK=64, 2-deep dbuf, STATIC buffers ----------
// (round-16 config: counted vmcnt(8), raw barriers, 8-slot XOR swizzle both sides)
template <bool PROJSTORE>
__device__ __forceinline__ void mgemm_body(
    const unsigned short* __restrict__ Ab, const unsigned short* __restrict__ Wt,
    const float* __restrict__ bias, void* __restrict__ out_, int n0, int m0)
{
    __shared__ unsigned short As0[128][64], As1[128][64];   // 4 x 16 KB
    __shared__ unsigned short Bs0[128][64], Bs1[128][64];
    const int t = threadIdx.x;
    const int w = t >> 6, lane = t & 63;
    const int wm = (w >> 1) * 64, wn = (w & 1) * 64;
    const int fr = lane & 15;
    const int fq = lane >> 4;

    const int sr = w * 8 + (lane >> 3);                       // +i*32
    const int sc = ((lane & 7) ^ ((lane >> 3) & 7)) * 8;      // pre-swizzled src col
    const unsigned short* aP = Ab + (size_t)(m0 + sr) * C_ + sc;
    const unsigned short* bP = Wt + (size_t)(n0 + sr) * C_ + sc;

    const int frm = (fr & 7);   // read-side swizzle key (row&7 == fr&7)

    f32x4 acc[4][4] = {};

#define STAGE(AB, BB, KT)                                                   \
    {                                                                       \
        _Pragma("unroll")                                                   \
        for (int i_ = 0; i_ < 4; ++i_) {                                    \
            gll16(aP + (size_t)i_ * 32 * C_ + (KT), &AB[i_ * 32 + w * 8][0]);\
            gll16(bP + (size_t)i_ * 32 * C_ + (KT), &BB[i_ * 32 + w * 8][0]);\
        }                                                                   \
    }

#define COMPUTE(AB, BB)                                                     \
    {                                                                       \
        _Pragma("unroll")                                                   \
        for (int c_ = 0; c_ < 2; ++c_) {                                    \
            const int rk_ = ((c_ * 4 + fq) ^ frm) * 8;                      \
            bf16x8 af_[4], bf_[4];                                          \
            _Pragma("unroll")                                               \
            for (int i_ = 0; i_ < 4; ++i_)                                  \
                af_[i_] = *(const bf16x8*)&AB[wm + i_ * 16 + fr][rk_];      \
            _Pragma("unroll")                                               \
            for (int j_ = 0; j_ < 4; ++j_)                                  \
                bf_[j_] = *(const bf16x8*)&BB[wn + j_ * 16 + fr][rk_];      \
            _Pragma("unroll")                                               \
            for (int i_ = 0; i_ < 4; ++i_)                                  \
                _Pragma("unroll")                                           \
                for (int j_ = 0; j_ < 4; ++j_)                              \
                    acc[i_][j_] = __builtin_amdgcn_mfma_f32_16x16x32_bf16(  \
                        af_[i_], bf_[j_], acc[i_][j_], 0, 0, 0);            \
        }                                                                   \
    }

    STAGE(As0, Bs0, 0);                       // prologue: tile 0 -> buf0
#pragma unroll 1
    for (int kt = 0; kt < C_; kt += 128) {
        STAGE(As1, Bs1, kt + 64);             // prefetch tile kt+64 -> buf1
        asm volatile("s_waitcnt vmcnt(8)" ::: "memory");   // tile kt done
        __builtin_amdgcn_s_barrier();
        COMPUTE(As0, Bs0);                    // compute tile kt
        __builtin_amdgcn_s_barrier();         // buf0 free
        if (kt + 128 < C_) {
            STAGE(As0, Bs0, kt + 128);        // prefetch tile kt+128 -> buf0
            asm volatile("s_waitcnt vmcnt(8)" ::: "memory");  // tile kt+64 done
        } else {
            asm volatile("s_waitcnt vmcnt(0)" ::: "memory");
        }
        __builtin_amdgcn_s_barrier();
        COMPUTE(As1, Bs1);                    // compute tile kt+64
        __builtin_amdgcn_s_barrier();         // buf1 free
    }
#undef STAGE
#undef COMPUTE

#pragma unroll
    for (int j = 0; j < 4; ++j) {
        const int gcol = n0 + wn + j * 16 + fr;
        const float bj = bias[gcol];
#pragma unroll
        for (int i = 0; i < 4; ++i) {
#pragma unroll
            for (int r = 0; r < 4; ++r) {
                const int grow = m0 + wm + i * 16 + fq * 4 + r;
                const float val = acc[i][j][r] + bj;
                if (PROJSTORE) {
                    const int bvb = grow >> 8, l = grow & 255;
                    const int hh = gcol >> 6, dh = gcol & 63;
                    ((unsigned short*)out_)[(((size_t)bvb * H_ + hh) * L_ + l) * DH_ + dh] =
                        (unsigned short)f2bfbits(val);
                } else {
                    ((float*)out_)[(size_t)grow * C_ + gcol] = val;
                }
            }
        }
    }
}

template <bool PROJSTORE>
__global__ __launch_bounds__(256) void mgemm_k(
    const unsigned short* __restrict__ Ab, const unsigned short* __restrict__ Wt,
    const float* __restrict__ bias, void* __restrict__ out_)
{
    mgemm_body<PROJSTORE>(Ab, Wt, bias, out_, blockIdx.x * 128, blockIdx.y * 128);
}

// three projection GEMMs, one launch, XCD-chunked
__global__ __launch_bounds__(256) void mgemm3_k(
    const unsigned short* __restrict__ cq, const unsigned short* __restrict__ ck,
    const unsigned short* __restrict__ cv, const unsigned short* __restrict__ Wtb,
    const float* __restrict__ bq, const float* __restrict__ bk, const float* __restrict__ bvv,
    unsigned short* __restrict__ qqw, unsigned short* __restrict__ kkw,
    unsigned short* __restrict__ vvw)
{
    const int b = blockIdx.x;
    const int swz = (b & 7) * 192 + (b >> 3);   // bijective: 1536 = 8*192
    const int which = swz >> 9;
    const int g = swz & 511;
    const unsigned short* A = (which == 0) ? cq : (which == 1) ? ck : cv;
    const unsigned short* W = Wtb + (size_t)which * (C_ * C_);
    const float* bias = (which == 0) ? bq : (which == 1) ? bk : bvv;
    unsigned short* outp = (which == 0) ? qqw : (which == 1) ? kkw : vvw;
    mgemm_body<true>(A, W, bias, (void*)outp, (g & 7) * 128, (g >> 3) * 128);
}

// final GEMM, 1D 512 blocks, XCD-chunked (cpx = 64)
__global__ __launch_bounds__(256) void mgemmf_k(
    const unsigned short* __restrict__ Ab, const unsigned short* __restrict__ Wt,
    const float* __restrict__ bias, float* __restrict__ out_)
{
    const int b = blockIdx.x;
    const int swz = (b & 7) * 64 + (b >> 3);    // bijective: 512 = 8*64
    mgemm_body<false>(Ab, Wt, bias, (void*)out_, (swz & 7) * 128, (swz >> 3) * 128);
}

// ---------- fused attention (round-15 verified) ----------
__global__ __launch_bounds__(256) void attn_k(
    const unsigned short* __restrict__ qq, const unsigned short* __restrict__ kk,
    const unsigned short* __restrict__ vv, const unsigned char* __restrict__ mpk,
    const float* __restrict__ alphas, unsigned short* __restrict__ atted)
{
    __shared__ unsigned short Vt[DH_][260];
    __shared__ unsigned int mkw[64];
    __shared__ float al[O_];
    const int h = blockIdx.x, bv = blockIdx.y;
    const int t = threadIdx.x;
    const int w = t >> 6, lane = t & 63;
    const int fr = lane & 31, hf = lane >> 5;
    const size_t hb = ((size_t)bv * H_ + h) * (L_ * DH_);

    {   // stage V row t transposed into Vt[:][t]
        const uint4* gv = (const uint4*)(vv + hb + (size_t)t * DH_);
#pragma unroll
        for (int i = 0; i < 8; ++i) {
            const uint4 wv = gv[i];
            const unsigned int ws4[4] = {wv.x, wv.y, wv.z, wv.w};
#pragma unroll
            for (int jd = 0; jd < 4; ++jd) {
                Vt[i * 8 + jd * 2 + 0][t] = (unsigned short)(ws4[jd] & 0xffffu);
                Vt[i * 8 + jd * 2 + 1][t] = (unsigned short)(ws4[jd] >> 16);
            }
        }
    }
    if (t < 64) mkw[t] = ((const unsigned int*)mpk)[bv * 64 + t];
    if (t < O_) al[t] = alphas[bv * O_ + t];
    __syncthreads();
    const float al0 = al[0], al1 = al[1], al2 = al[2], al3 = al[3];

#pragma unroll 1
    for (int qt = 0; qt < 2; ++qt) {
        const int q32 = w * 64 + qt * 32;
        bf16x8 qf[4];
#pragma unroll
        for (int st = 0; st < 4; ++st)
            qf[st] = *(const bf16x8*)(qq + hb + (size_t)(q32 + fr) * DH_ + st * 16 + hf * 8);

        // ---- pass 1: masked T sums ----
        float T0 = 0.f, T1 = 0.f, T2 = 0.f, T3 = 0.f;
#pragma unroll 1
        for (int j = 0; j < 8; ++j) {
            bf16x8 kf[4];
#pragma unroll
            for (int st = 0; st < 4; ++st)
                kf[st] = *(const bf16x8*)(kk + hb + (size_t)(j * 32 + fr) * DH_ + st * 16 + hf * 8);
            f32x16 s = {};
#pragma unroll
            for (int st = 0; st < 4; ++st)
                s = __builtin_amdgcn_mfma_f32_32x32x16_bf16(kf[st], qf[st], s, 0, 0, 0);
#pragma unroll
            for (int c = 0; c < 4; ++c) {
                const unsigned int iv = (~mkw[j * 8 + c * 2 + hf]) & 0x0F0F0F0Fu;
#pragma unroll
                for (int r = 0; r < 4; ++r) {
                    const float e = __expf(s[c * 4 + r] * 0.125f);
                    const unsigned int nib = iv >> (r * 8);
                    T0 = fmaf(e, (float)( nib       & 1u), T0);
                    T1 = fmaf(e, (float)((nib >> 1) & 1u), T1);
                    T2 = fmaf(e, (float)((nib >> 2) & 1u), T2);
                    T3 = fmaf(e, (float)((nib >> 3) & 1u), T3);
                }
            }
        }
        T0 += __shfl_xor(T0, 32, 64);
        T1 += __shfl_xor(T1, 32, 64);
        T2 += __shfl_xor(T2, 32, 64);
        T3 += __shfl_xor(T3, 32, 64);
        const float c0 = al0 * __builtin_amdgcn_rcpf(fmaxf(T0, 1e-30f));
        const float c1 = al1 * __builtin_amdgcn_rcpf(fmaxf(T1, 1e-30f));
        const float c2 = al2 * __builtin_amdgcn_rcpf(fmaxf(T2, 1e-30f));
        const float c3 = al3 * __builtin_amdgcn_rcpf(fmaxf(T3, 1e-30f));

        // ---- pass 2: recompute S, weight, PV ----
        f32x16 o0 = {};
        f32x16 o1 = {};
#pragma unroll 1
        for (int j = 0; j < 8; ++j) {
            bf16x8 kf[4];
#pragma unroll
            for (int st = 0; st < 4; ++st)
                kf[st] = *(const bf16x8*)(kk + hb + (size_t)(j * 32 + fr) * DH_ + st * 16 + hf * 8);
            f32x16 s = {};
#pragma unroll
            for (int st = 0; st < 4; ++st)
                s = __builtin_amdgcn_mfma_f32_32x32x16_bf16(kf[st], qf[st], s, 0, 0, 0);

            unsigned int pe[4][2];
#pragma unroll
            for (int c = 0; c < 4; ++c) {
                const unsigned int iv = (~mkw[j * 8 + c * 2 + hf]) & 0x0F0F0F0Fu;
                float p[4];
#pragma unroll
                for (int r = 0; r < 4; ++r) {
                    const float e = __expf(s[c * 4 + r] * 0.125f);
                    const unsigned int nib = iv >> (r * 8);
                    float cf =      c0 * (float)( nib       & 1u);
                    cf = fmaf(c1, (float)((nib >> 1) & 1u), cf);
                    cf = fmaf(c2, (float)((nib >> 2) & 1u), cf);
                    cf = fmaf(c3, (float)((nib >> 3) & 1u), cf);
                    p[r] = e * cf;
                }
                pe[c][0] = cvtpk_bf16(p[0], p[1]);
                pe[c][1] = cvtpk_bf16(p[2], p[3]);
            }
#pragma unroll
            for (int b = 0; b < 2; ++b) {
                const unsigned int qe0 = pe[2 * b][0],     qe1 = pe[2 * b][1];
                const unsigned int qo0 = pe[2 * b + 1][0], qo1 = pe[2 * b + 1][1];
                const unsigned int xe0 = (unsigned int)__shfl_xor((int)qe0, 32, 64);
                const unsigned int xe1 = (unsigned int)__shfl_xor((int)qe1, 32, 64);
                const unsigned int xo0 = (unsigned int)__shfl_xor((int)qo0, 32, 64);
                const unsigned int xo1 = (unsigned int)__shfl_xor((int)qo1, 32, 64);
                union { unsigned int d[4]; bf16x8 v; } pa;
                pa.d[0] = hf ? xo0 : qe0;
                pa.d[1] = hf ? xo1 : qe1;
                pa.d[2] = hf ? qo0 : xe0;
                pa.d[3] = hf ? qo1 : xe1;

                const int kc = j * 32 + b * 16 + hf * 8;
                union { struct { bf16x4 lo, hi; } p2; bf16x8 v; } v0u, v1u;
                v0u.p2.lo = *(const bf16x4*)&Vt[ 0 + fr][kc];
                v0u.p2.hi = *(const bf16x4*)&Vt[ 0 + fr][kc + 4];
                v1u.p2.lo = *(const bf16x4*)&Vt[32 + fr][kc];
                v1u.p2.hi = *(const bf16x4*)&Vt[32 + fr][kc + 4];
                o0 = __builtin_amdgcn_mfma_f32_32x32x16_bf16(pa.v, v0u.v, o0, 0, 0, 0);
                o1 = __builtin_amdgcn_mfma_f32_32x32x16_bf16(pa.v, v1u.v, o1, 0, 0, 0);
            }
        }
#pragma unroll
        for (int reg = 0; reg < 16; ++reg) {
            const int qrow = q32 + (reg & 3) + 8 * (reg >> 2) + 4 * hf;
            unsigned short* dst = atted + ((size_t)bv * L_ + qrow) * C_ + h * DH_;
            dst[fr]      = (unsigned short)f2bfbits(o0[reg]);
            dst[32 + fr] = (unsigned short)f2bfbits(o1[reg]);
        }
    }
}

// ---------- launch ----------
extern "C" void kernel_launch(void* const* d_in, const int* in_sizes, int n_in,
                              void* d_out, int out_size, void* d_ws, size_t ws_size,
                              hipStream_t stream)
{
    (void)in_sizes; (void)n_in; (void)out_size;
    const float* v   = (const float*)d_in[0];
    const float* k   = (const float*)d_in[1];
    const float* q   = (const float*)d_in[2];
    const void*  msk = d_in[3];
    const float* tau = (const float*)d_in[4];
    const float* gum = (const float*)d_in[6];
    const float* Wv  = (const float*)d_in[7];
    const float* bvp = (const float*)d_in[8];
    const float* Wk  = (const float*)d_in[9];
    const float* bkp = (const float*)d_in[10];
    const float* Wq  = (const float*)d_in[11];
    const float* bqp = (const float*)d_in[12];
    const float* Wm  = (const float*)d_in[13];
    const float* bmp = (const float*)d_in[14];
    const float* W1  = (const float*)d_in[15];
    const float* W2  = (const float*)d_in[16];
    const float* b2  = (const float*)d_in[17];
    float* out = (float*)d_out;

    char* ws = (char*)d_ws;

    if (ws_size >= (size_t)128 * MB_) {
        float* alphas       = (float*)ws;
        unsigned char* mpk  = (unsigned char*)(ws + 1024);
        float* pooled       = (float*)(ws + 16384);
        float* pbuf2        = (float*)(ws + 147456);
        float* pbuf         = (float*)(ws + 1196032);
        unsigned short* Wtb = (unsigned short*)(ws + (size_t)4 * MB_);   // 4 x 2 MB
        unsigned short* cq  = (unsigned short*)(ws + (size_t)14 * MB_);  // 16 MB each
        unsigned short* ck  = (unsigned short*)(ws + (size_t)30 * MB_);
        unsigned short* cv  = (unsigned short*)(ws + (size_t)46 * MB_);
        unsigned short* qqw = (unsigned short*)(ws + (size_t)62 * MB_);
        unsigned short* kkw = (unsigned short*)(ws + (size_t)78 * MB_);
        unsigned short* vvw = (unsigned short*)(ws + (size_t)94 * MB_);
        unsigned short* atw = (unsigned short*)(ws + (size_t)110 * MB_);

        hipLaunchKernelGGL(prep_k, dim3(13572), dim3(256), 0, stream,
                           q, k, v, msk, Wq, Wk, Wv, Wm, cq, ck, cv, pbuf2, mpk, Wtb);
        hipLaunchKernelGGL(poolr_k, dim3(128), dim3(256), 0, stream, pbuf2, pooled);
        hipLaunchKernelGGL(mlp1_k, dim3(16, 32), dim3(256), 0, stream, pooled, W1, pbuf);
        hipLaunchKernelGGL(mlp2_k, dim3(BV_), dim3(256), 0, stream,
                           pbuf, W2, b2, gum, tau, alphas);
        hipLaunchKernelGGL(mgemm3_k, dim3(1536), dim3(256), 0, stream,
                           cq, ck, cv, Wtb, bqp, bkp, bvp, qqw, kkw, vvw);
        hipLaunchKernelGGL(attn_k, dim3(H_, BV_), dim3(256), 0, stream,
                           qqw, kkw, vvw, mpk, alphas, atw);
        hipLaunchKernelGGL(mgemmf_k, dim3(512), dim3(256), 0, stream,
                           atw, Wtb + (size_t)3 * (C_ * C_), bmp, out);
    } else {
        // fallback: serial layout (66 MB)
        float* alphas       = (float*)ws;
        unsigned char* mpk  = (unsigned char*)(ws + 1024);
        float* pooled       = (float*)(ws + 16384);
        float* pbuf2        = (float*)(ws + 147456);
        float* pbuf         = (float*)(ws + 1196032);
        unsigned short* Wt  = (unsigned short*)(ws + 16384);
        unsigned short* qqw = (unsigned short*)(ws + 2113536);
        unsigned short* kkw = qqw + (size_t)M_ * C_;
        unsigned short* vvw = kkw + (size_t)M_ * C_;
        unsigned short* atw = vvw + (size_t)M_ * C_;

        hipLaunchKernelGGL(pools_k, dim3(256), dim3(256), 0, stream, v, pbuf2);
        hipLaunchKernelGGL(poolr_k, dim3(128), dim3(256), 0, stream, pbuf2, pooled);
        hipLaunchKernelGGL(mlp1_k, dim3(16, 32), dim3(256), 0, stream, pooled, W1, pbuf);
        hipLaunchKernelGGL(mlp2_k, dim3(BV_), dim3(256), 0, stream,
                           pbuf, W2, b2, gum, tau, alphas);
        hipLaunchKernelGGL(maskpack_k, dim3(1), dim3(1024), 0, stream, msk, mpk);

        hipLaunchKernelGGL(conv_k, dim3(4096), dim3(256), 0, stream, q, atw);
        hipLaunchKernelGGL(wprep_k, dim3(16, 16), dim3(256), 0, stream, Wq, Wt);
        hipLaunchKernelGGL((mgemm_k<true>), dim3(8, 64), dim3(256), 0, stream,
                           atw, Wt, bqp, (void*)qqw);
        hipLaunchKernelGGL(conv_k, dim3(4096), dim3(256), 0, stream, k, atw);
        hipLaunchKernelGGL(wprep_k, dim3(16, 16), dim3(256), 0, stream, Wk, Wt);
        hipLaunchKernelGGL((mgemm_k<true>), dim3(8, 64), dim3(256), 0, stream,
                           atw, Wt, bkp, (void*)kkw);
        hipLaunchKernelGGL(conv_k, dim3(4096), dim3(256), 0, stream, v, atw);
        hipLaunchKernelGGL(wprep_k, dim3(16, 16), dim3(256), 0, stream, Wv, Wt);
        hipLaunchKernelGGL((mgemm_k<true>), dim3(8, 64), dim3(256), 0, stream,
                           atw, Wt, bvp, (void*)vvw);

        hipLaunchKernelGGL(attn_k, dim3(H_, BV_), dim3(256), 0, stream,
                           qqw, kkw, vvw, mpk, alphas, atw);

        hipLaunchKernelGGL(wprep_k, dim3(16, 16), dim3(256), 0, stream, Wm, Wt);
        hipLaunchKernelGGL((mgemm_k<false>), dim3(8, 64), dim3(256), 0, stream,
                           atw, Wt, bmp, (void*)out);
    }
}